// Round 11
// baseline (5270.384 us; speedup 1.0000x reference)
//
#include <hip/hip_runtime.h>
#include <stdint.h>

#define N_PTS 65536
#define DIMS 6
#define NSAMP 2048
#define NGRP 64
#define EMB 512
#define ROWS (NSAMP*NGRP)
#define EPS_BN 1e-5f

#define FIRST_MODE 0

typedef __attribute__((ext_vector_type(8))) short short8;
typedef __attribute__((ext_vector_type(4))) float float4v;

__device__ __forceinline__ unsigned short f2bf(float f) {
  unsigned u = __float_as_uint(f);
  u += 0x7FFFu + ((u >> 16) & 1u);   // RNE
  return (unsigned short)(u >> 16);
}

// merge two descending-sorted top-2 pairs -> descending top-2 (keys unique)
__device__ __forceinline__ void mrg2(unsigned long long &a0, unsigned long long &a1,
                                     unsigned long long b0, unsigned long long b1) {
  bool agt = a0 > b0;
  unsigned long long hi  = agt ? a0 : b0;
  unsigned long long lo  = agt ? b0 : a0;
  unsigned long long sec = agt ? a1 : b1;
  a0 = hi;
  a1 = lo > sec ? lo : sec;
}

// ---------------- Threefry-2x32, 20 rounds (JAX-compatible) ----------------
__device__ __forceinline__ void tf2x32(unsigned k0, unsigned k1, unsigned &x0, unsigned &x1) {
  unsigned ks[3] = {k0, k1, k0 ^ k1 ^ 0x1BD11BDAu};
  const unsigned R[8] = {13,15,26,6,17,29,16,24};
  x0 += ks[0]; x1 += ks[1];
#pragma unroll
  for (int g = 0; g < 5; ++g) {
#pragma unroll
    for (int j = 0; j < 4; ++j) {
      unsigned r = R[(g & 1) * 4 + j];
      x0 += x1;
      x1 = (x1 << r) | (x1 >> (32 - r));
      x1 ^= x0;
    }
    x0 += ks[(g + 1) % 3];
    x1 += ks[(g + 2) % 3] + (unsigned)(g + 1);
  }
}

__device__ __forceinline__ int compute_first(unsigned seed) {
  unsigned k0 = 0u, k1 = seed;
  unsigned s0, s1;
#if (FIRST_MODE == 0) || (FIRST_MODE == 1)
  { unsigned a0 = 0u, a1 = 1u; tf2x32(k0, k1, a0, a1); s0 = a0; s1 = a1; }
#else
  { unsigned p0 = 0u, p1 = 2u; tf2x32(k0, k1, p0, p1);
    unsigned q0 = 1u, q1 = 3u; tf2x32(k0, k1, q0, q1);
    s0 = p1; s1 = q1; }
#endif
  unsigned b0 = 0u, b1v = 0u; tf2x32(s0, s1, b0, b1v);
#if (FIRST_MODE == 0) || (FIRST_MODE == 3)
  unsigned bits = b0 ^ b1v;
#else
  unsigned bits = b0;
#endif
  return (int)(bits & 0xFFFFu);
}

// ---------------- geometry ---------------------------------------------------
#define FPSB 16                      // FPS blocks; 2 slots/block/round
#define MEGA_BLOCKS 256              // 16 FPS + 240 workers
#define FPS_PPT 4                    // 65536 / (16*1024)
#define GB_CAND 512
#define H1B_S 520
#define MEGA_LDS 90112               // forces 1 block/CU
#define SLOT_N (2047*2*FPSB)         // 65504 u64

// ---------------- init: xyzw, slots, stats, W2T(bf16), first idx ------------
__global__ __launch_bounds__(256) void k_init(const float* __restrict__ pts,
    const float* __restrict__ W2, const int* __restrict__ seed_arr,
    unsigned long long* __restrict__ slot, float* __restrict__ stats,
    float* __restrict__ st2, unsigned short* __restrict__ W2T,
    float4* __restrict__ xyzw, int* __restrict__ sampled) {
  int tid = blockIdx.x * 256 + threadIdx.x;        // 65536 threads
  if (tid < N_PTS) {
    float x = pts[tid*6], y = pts[tid*6+1], z = pts[tid*6+2];
    float p2 = __fadd_rn(__fadd_rn(__fmul_rn(x,x), __fmul_rn(y,y)), __fmul_rn(z,z));
    xyzw[tid] = make_float4(x, y, z, p2);
  }
#pragma unroll
  for (int i = 0; i < 4; ++i) {      // W2T[c][k] = bf16(W2[k][c])
    int e = tid + i*65536;
    int c = e >> 9, k = e & 511;
    W2T[e] = f2bf(W2[k*EMB + c]);
  }
  if (tid < SLOT_N) slot[tid] = 0ull;
  if (tid < 4*EMB) stats[tid] = 0.f;
  if (tid < 32*1024) st2[tid] = 0.f;
  if (tid >= 1 && tid < NSAMP) sampled[tid] = -1;  // sentinel for workers
  if (tid == 0) sampled[0] = compute_first((unsigned)seed_arr[0]);
}

// ---------------- mega: speculative FPS + group/stats workers ----------------
// FPS with top-2 speculation: each round publishes the block's true top-2
// packed keys. After the global top-2 (g0,g1) merge, every block checks
// d(g1,g0) >= pd(g1) (exact fp32, deterministic, replicated). If true, g1 is
// PROVABLY the next winner too (all other keys < g1's and keys only shrink),
// so the round advances 2 iterations with one cross-block round trip.
__global__ __launch_bounds__(1024) void k_mega(
    const float4* __restrict__ xyzw, const float* __restrict__ pts,
    const float* __restrict__ W1, const float* __restrict__ b1,
    unsigned long long* __restrict__ slot, int* __restrict__ sampled,
    int* __restrict__ groups, float* __restrict__ gsum, float* __restrict__ gss) {
  extern __shared__ __align__(16) char smraw[];
  const int t = threadIdx.x;
  if (blockIdx.x < FPSB) {
    // ------------------ FPS role ------------------
    unsigned long long* wred = (unsigned long long*)smraw;            // [2][16][2]
    volatile unsigned long long* winLDS =
        (volatile unsigned long long*)(smraw + 512);                  // [2]
    const int b = blockIdx.x;
    const int T = b*1024 + t;
    const int lane = t & 63, wid = t >> 6;
    float px[FPS_PPT], py[FPS_PPT], pz[FPS_PPT], pd[FPS_PPT];
    unsigned nidxu[FPS_PPT];
#pragma unroll
    for (int i = 0; i < FPS_PPT; ++i) {
      float4 p = xyzw[T + 16384*i];
      px[i] = p.x; py[i] = p.y; pz[i] = p.z; pd[i] = __builtin_inff();
      nidxu[i] = 0xFFFFFFFFu - (unsigned)(T + 16384*i);
    }
    if (t == 0) { winLDS[0] = 0ull; winLDS[1] = 0ull; }
    int ns = 1;
    int pend0 = sampled[0], pend1 = 0, pendm = 1;
    int r = 0;
    __syncthreads();
    while (ns < NSAMP) {
      const int p = r & 1;
      float4 cc0 = xyzw[pend0];
      float4 cc1 = cc0;
      if (pendm == 2) cc1 = xyzw[pend1];
      unsigned long long b0v = 1ull, b1v = 1ull;
#pragma unroll
      for (int i = 0; i < FPS_PPT; ++i) {
        float dx = __fsub_rn(px[i], cc0.x);
        float dy = __fsub_rn(py[i], cc0.y);
        float dz = __fsub_rn(pz[i], cc0.z);
        float d = __fadd_rn(__fadd_rn(__fmul_rn(dx,dx), __fmul_rn(dy,dy)), __fmul_rn(dz,dz));
        float pdn = fminf(pd[i], d);
        if (pendm == 2) {
          float ex = __fsub_rn(px[i], cc1.x);
          float ey = __fsub_rn(py[i], cc1.y);
          float ez = __fsub_rn(pz[i], cc1.z);
          float e = __fadd_rn(__fadd_rn(__fmul_rn(ex,ex), __fmul_rn(ey,ey)), __fmul_rn(ez,ez));
          pdn = fminf(pdn, e);
        }
        pd[i] = pdn;
        unsigned long long k = ((unsigned long long)__float_as_uint(pdn) << 32)
                             | (unsigned long long)nidxu[i];
        bool gt = k > b0v;
        unsigned long long nb1 = gt ? b0v : (k > b1v ? k : b1v);
        b0v = gt ? k : b0v;
        b1v = nb1;
      }
#pragma unroll
      for (int off = 32; off >= 1; off >>= 1) {
        unsigned long long o0 = __shfl_xor(b0v, off, 64);
        unsigned long long o1 = __shfl_xor(b1v, off, 64);
        mrg2(b0v, b1v, o0, o1);
      }
      if (lane == 0) { wred[p*32 + wid*2] = b0v; wred[p*32 + wid*2 + 1] = b1v; }
      __syncthreads();
      int mloc, w0, w1s;
      if (wid == 0) {
        if (lane == 0) winLDS[1-p] = 0ull;   // safe: all waves past prev spin
        unsigned long long m0 = wred[p*32 + (lane & 15)*2];
        unsigned long long m1 = wred[p*32 + (lane & 15)*2 + 1];
#pragma unroll
        for (int off = 8; off >= 1; off >>= 1) {
          unsigned long long o0 = __shfl_xor(m0, off, 64);
          unsigned long long o1 = __shfl_xor(m1, off, 64);
          mrg2(m0, m1, o0, o1);
        }
        if (lane == 0) {
          __hip_atomic_store(&slot[r*2*FPSB + b*2], m0,
                             __ATOMIC_RELAXED, __HIP_MEMORY_SCOPE_AGENT);
          __hip_atomic_store(&slot[r*2*FPSB + b*2 + 1], m1,
                             __ATOMIC_RELAXED, __HIP_MEMORY_SCOPE_AGENT);
        }
        unsigned long long v0 = 0ull, v1 = 0ull;
        if (lane < FPSB) {
          const unsigned long long* sp = &slot[r*2*FPSB + lane*2];
          v0 = __hip_atomic_load(sp,   __ATOMIC_RELAXED, __HIP_MEMORY_SCOPE_AGENT);
          v1 = __hip_atomic_load(sp+1, __ATOMIC_RELAXED, __HIP_MEMORY_SCOPE_AGENT);
          while (v0 == 0ull || v1 == 0ull) {
            if (v0 == 0ull) v0 = __hip_atomic_load(sp,   __ATOMIC_RELAXED, __HIP_MEMORY_SCOPE_AGENT);
            if (v1 == 0ull) v1 = __hip_atomic_load(sp+1, __ATOMIC_RELAXED, __HIP_MEMORY_SCOPE_AGENT);
          }
        }
#pragma unroll
        for (int off = 8; off >= 1; off >>= 1) {
          unsigned long long o0 = __shfl_xor(v0, off, 64);
          unsigned long long o1 = __shfl_xor(v1, off, 64);
          mrg2(v0, v1, o0, o1);
        }
        v0 = __shfl(v0, 0, 64);
        v1 = __shfl(v1, 0, 64);
        w0 = (int)(0xFFFFFFFFu - (unsigned)(v0 & 0xFFFFFFFFull));
        mloc = 1; w1s = 0;
        if (ns + 2 <= NSAMP) {            // speculation: is g1 the next winner?
          int i1 = (int)(0xFFFFFFFFu - (unsigned)(v1 & 0xFFFFFFFFull));
          float pdk = __uint_as_float((unsigned)(v1 >> 32));
          float4 pw = xyzw[w0];
          float4 pq = xyzw[i1];
          float dx = __fsub_rn(pq.x, pw.x);
          float dy = __fsub_rn(pq.y, pw.y);
          float dz = __fsub_rn(pq.z, pw.z);
          float d = __fadd_rn(__fadd_rn(__fmul_rn(dx,dx), __fmul_rn(dy,dy)), __fmul_rn(dz,dz));
          if (!(d < pdk)) { mloc = 2; w1s = i1; }   // pd(g1) survives -> proven winner
        }
        if (lane == 0) {
          if (b == 0) {
            __hip_atomic_store((unsigned*)&sampled[ns], (unsigned)w0,
                               __ATOMIC_RELAXED, __HIP_MEMORY_SCOPE_AGENT);
            if (mloc == 2)
              __hip_atomic_store((unsigned*)&sampled[ns+1], (unsigned)w1s,
                                 __ATOMIC_RELAXED, __HIP_MEMORY_SCOPE_AGENT);
          }
          winLDS[p] = (1ull << 63) | ((unsigned long long)mloc << 32)
                    | ((unsigned long long)((unsigned)w0 << 16))
                    | (unsigned long long)(unsigned)w1s;
        }
      } else {
        unsigned long long wb = winLDS[p];
        while (wb == 0ull) { __builtin_amdgcn_s_sleep(1); wb = winLDS[p]; }
        mloc = (int)((wb >> 32) & 3ull);
        w0   = (int)((wb >> 16) & 0xFFFFull);
        w1s  = (int)(wb & 0xFFFFull);
      }
      ns += mloc;
      pend0 = w0; pend1 = w1s; pendm = mloc;
      ++r;
    }
  } else {
    // ------------------ worker role: group + bn1 stats ------------------
    unsigned* hist  = (unsigned*)smraw;              // 8192
    unsigned* scan  = (unsigned*)(smraw + 32768);    // 1024
    unsigned* candK = (unsigned*)(smraw + 36864);    // 512
    int*      candI = (int*)(smraw + 38912);         // 512
    float*    feat  = (float*)(smraw + 40960);       // 768
    float*    cf    = (float*)(smraw + 44032);       // 8
    unsigned* ctl   = (unsigned*)(smraw + 44064);    // outcnt, candcnt
    volatile int* binfo = (volatile int*)(smraw + 44080); // B, bef, sid
    const int wkr = blockIdx.x - FPSB;               // 0..239
    for (int s = wkr; s < NSAMP; s += MEGA_BLOCKS - FPSB) {
      if (t == 0) {
        unsigned v = __hip_atomic_load((const unsigned*)&sampled[s],
                        __ATOMIC_RELAXED, __HIP_MEMORY_SCOPE_AGENT);
        while (v == 0xFFFFFFFFu) {
          __builtin_amdgcn_s_sleep(64);
          v = __hip_atomic_load((const unsigned*)&sampled[s],
                  __ATOMIC_RELAXED, __HIP_MEMORY_SCOPE_AGENT);
        }
        binfo[2] = (int)v;
        ctl[0] = 0u; ctl[1] = 0u;
      }
      for (int k = t; k < 8192; k += 1024) hist[k] = 0u;
      __syncthreads();
      const int sid = binfo[2];
      float4 c4 = xyzw[sid];
      const float cx=c4.x, cy=c4.y, cz=c4.z, c2=c4.w;
      for (int i = 0; i < N_PTS/1024; ++i) {
        int j = i*1024 + t;
        float4 p = xyzw[j];
        float dot = __fadd_rn(__fadd_rn(__fmul_rn(cx,p.x),__fmul_rn(cy,p.y)),__fmul_rn(cz,p.z));
        float d = __fsub_rn(__fadd_rn(c2, p.w), __fmul_rn(2.0f, dot));
        unsigned kb = __float_as_uint(d);
        kb ^= ((unsigned)((int)kb >> 31)) | 0x80000000u;
        atomicAdd(&hist[kb >> 19], 1u);
      }
      __syncthreads();
      unsigned ch = 0u;
      for (int k = 0; k < 8; ++k) ch += hist[t*8 + k];
      scan[t] = ch;
      __syncthreads();
      for (int off = 1; off < 1024; off <<= 1) {
        unsigned vv = (t >= off) ? scan[t - off] : 0u;
        __syncthreads();
        scan[t] += vv;
        __syncthreads();
      }
      unsigned inc = scan[t], before = inc - ch;
      if (before < NGRP && inc >= NGRP) {
        unsigned c = before;
        for (int k = 0; k < 8; ++k) {
          unsigned nb = hist[t*8 + k];
          if (c + nb >= NGRP) { binfo[0] = t*8 + k; binfo[1] = (int)c; break; }
          c += nb;
        }
      }
      __syncthreads();
      const unsigned B = (unsigned)binfo[0];
      const int bef = binfo[1];
      for (int i = 0; i < N_PTS/1024; ++i) {
        int j = i*1024 + t;
        float4 p = xyzw[j];
        float dot = __fadd_rn(__fadd_rn(__fmul_rn(cx,p.x),__fmul_rn(cy,p.y)),__fmul_rn(cz,p.z));
        float d = __fsub_rn(__fadd_rn(c2, p.w), __fmul_rn(2.0f, dot));
        unsigned kb = __float_as_uint(d);
        kb ^= ((unsigned)((int)kb >> 31)) | 0x80000000u;
        unsigned bin = kb >> 19;
        if (bin < B) {
          unsigned pos = atomicAdd(&ctl[0], 1u);
          groups[s*NGRP + pos] = j;
        } else if (bin == B) {
          unsigned ci = atomicAdd(&ctl[1], 1u);
          if (ci < GB_CAND) { candK[ci] = kb; candI[ci] = j; }
        }
      }
      __syncthreads();
      int M = ctl[1] < GB_CAND ? (int)ctl[1] : GB_CAND;
      int need = NGRP - bef;
      for (int c = t; c < M; c += 1024) {
        unsigned mk = candK[c]; int mi = candI[c];
        int rank = 0;
        for (int q = 0; q < M; ++q) {
          unsigned qk = candK[q];
          rank += (qk < mk || (qk == mk && candI[q] < mi)) ? 1 : 0;
        }
        if (rank < need) {
          unsigned pos = atomicAdd(&ctl[0], 1u);
          groups[s*NGRP + pos] = candI[c];
        }
      }
      __syncthreads();
      if (t == 0) {
        while (ctl[0] < NGRP) { groups[s*NGRP + ctl[0]] = 0; ctl[0]++; }
      }
      __syncthreads();
      if (t < DIMS) cf[t] = pts[sid*6 + t];
      __syncthreads();
      if (t < NGRP) {
        int g = groups[s*NGRP + t];
#pragma unroll
        for (int k = 0; k < DIMS; ++k) {
          float v = pts[g*6 + k];
          feat[t*12 + k] = v - cf[k];
          feat[t*12 + 6 + k] = v;
        }
      }
      __syncthreads();
      if (t < EMB) {
        float w[12];
#pragma unroll
        for (int k = 0; k < 12; ++k) w[k] = W1[k*EMB + t];
        float b = b1[t];
        float sum = 0.f, ss = 0.f;
        for (int r = 0; r < NGRP; ++r) {
          float y = b;
#pragma unroll
          for (int k = 0; k < 12; ++k) y += feat[r*12+k] * w[k];
          sum += y; ss += y*y;
        }
        atomicAdd(&gsum[t], sum);
        atomicAdd(&gss[t], ss);
      }
      __syncthreads();   // smraw reused next s
    }
  }
}

// ---------------- bn1 finalize ----------------------------------------------
__global__ __launch_bounds__(EMB) void k_finalize(const float* __restrict__ gsum,
    const float* __restrict__ gss, const float* __restrict__ scale,
    const float* __restrict__ bias, float* __restrict__ ac) {
  int c = threadIdx.x;
  float inv = 1.f / (float)ROWS;
  float mean = gsum[c] * inv;
  float var = gss[c] * inv - mean*mean;
  var = var < 0.f ? 0.f : var;
  float a = scale[c] * rsqrtf(var + EPS_BN);
  ac[c] = a; ac[EMB + c] = bias[c] - mean * a;
}

// ---------------- bn2 finalize from 32-sliced stats -------------------------
__global__ __launch_bounds__(EMB) void k_finalize2(const float* __restrict__ st2,
    const float* __restrict__ scale, const float* __restrict__ bias,
    float* __restrict__ ac) {
  int c = threadIdx.x;
  float sum = 0.f, ss = 0.f;
  for (int i = 0; i < 32; ++i) {
    sum += st2[i*1024 + c];
    ss  += st2[i*1024 + 512 + c];
  }
  float inv = 1.f / (float)ROWS;
  float mean = sum * inv;
  float var = ss * inv - mean*mean;
  var = var < 0.f ? 0.f : var;
  float a = scale[c] * rsqrtf(var + EPS_BN);
  ac[c] = a; ac[EMB + c] = bias[c] - mean * a;
}

// ---------------- fused MLP: fp32 GEMM1 -> bf16 MFMA GEMM2 ------------------
__global__ __launch_bounds__(512, 4) void k_mlp(const float* __restrict__ pts,
    const int* __restrict__ sampled, const int* __restrict__ groups,
    const float* __restrict__ W1, const float* __restrict__ b1,
    const float* __restrict__ ac1, const unsigned short* __restrict__ W2T,
    const float* __restrict__ b2, const float* __restrict__ scale2,
    float* __restrict__ st2, float* __restrict__ y2sel) {
  const int s = blockIdx.x, t = threadIdx.x;
  extern __shared__ __align__(16) char smc[];
  float* feat = (float*)smc;                       // 768 f
  float* cf   = (float*)(smc + 3072);              // 8 f
  unsigned short* h1b = (unsigned short*)(smc + 3104);  // 64 x 520 bf16
  if (t < DIMS) cf[t] = pts[sampled[s]*6 + t];
  __syncthreads();
  if (t < NGRP) {
    int g = groups[s*NGRP + t];
#pragma unroll
    for (int k = 0; k < DIMS; ++k) {
      float v = pts[g*6 + k];
      feat[t*12+k]   = v - cf[k];
      feat[t*12+6+k] = v;
    }
  }
  __syncthreads();
  {
    float w[12];
#pragma unroll
    for (int k = 0; k < 12; ++k) w[k] = W1[k*EMB + t];
    float b = b1[t], a1 = ac1[t], c1 = ac1[EMB + t];
    for (int r = 0; r < NGRP; ++r) {
      float y = b;
#pragma unroll
      for (int k = 0; k < 12; ++k) y += feat[r*12+k] * w[k];
      float hv = a1*y + c1;
      h1b[r*H1B_S + t] = f2bf(hv > 0.f ? hv : 0.f);
    }
  }
  __syncthreads();
  const int lane = t & 63, w = t >> 6;
  const int quad = lane >> 4, l16 = lane & 15;
  float4v acc[4][4];
#pragma unroll
  for (int nt = 0; nt < 4; ++nt) {
    float bv = b2[(w*4+nt)*16 + l16];
#pragma unroll
    for (int mt = 0; mt < 4; ++mt)
      acc[nt][mt] = (float4v){bv, bv, bv, bv};
  }
  for (int kc = 0; kc < 16; ++kc) {
    const int kb = kc*32 + quad*8;
    short8 af[4];
#pragma unroll
    for (int mt = 0; mt < 4; ++mt)
      af[mt] = *(const short8*)&h1b[(mt*16 + l16)*H1B_S + kb];
#pragma unroll
    for (int nt = 0; nt < 4; ++nt) {
      const int c = (w*4+nt)*16 + l16;
      short8 bf = *(const short8*)&W2T[c*EMB + kb];
#pragma unroll
      for (int mt = 0; mt < 4; ++mt)
        acc[nt][mt] = __builtin_amdgcn_mfma_f32_16x16x32_bf16(af[mt], bf, acc[nt][mt], 0, 0, 0);
    }
  }
#pragma unroll
  for (int nt = 0; nt < 4; ++nt) {
    float sm_ = 0.f, ss_ = 0.f, mx = -__builtin_inff(), mn = __builtin_inff();
#pragma unroll
    for (int mt = 0; mt < 4; ++mt)
#pragma unroll
      for (int i = 0; i < 4; ++i) {
        float v = acc[nt][mt][i];
        sm_ += v; ss_ += v*v;
        mx = fmaxf(mx, v); mn = fminf(mn, v);
      }
#pragma unroll
    for (int off = 16; off <= 32; off <<= 1) {
      sm_ += __shfl_xor(sm_, off, 64);
      ss_ += __shfl_xor(ss_, off, 64);
      mx = fmaxf(mx, __shfl_xor(mx, off, 64));
      mn = fminf(mn, __shfl_xor(mn, off, 64));
    }
    if (quad == 0) {
      int c = (w*4+nt)*16 + l16;
      atomicAdd(&st2[(s & 31)*1024 + c], sm_);
      atomicAdd(&st2[(s & 31)*1024 + 512 + c], ss_);
      y2sel[s*EMB + c] = (scale2[c] >= 0.f) ? mx : mn;
    }
  }
}

// ---------------- epilogue: bn2+relu on pooled extremum ---------------------
__global__ __launch_bounds__(256) void k_out(const float* __restrict__ y2sel,
    const float* __restrict__ ac2, float* __restrict__ out) {
  int i = blockIdx.x*256 + threadIdx.x;
  int c = i & (EMB-1);
  float a = ac2[c], cc = ac2[EMB + c];
  float v = a*y2sel[i] + cc;
  out[i] = v > 0.f ? v : 0.f;
}

extern "C" void kernel_launch(void* const* d_in, const int* in_sizes, int n_in,
                              void* d_out, int out_size, void* d_ws, size_t ws_size,
                              hipStream_t stream) {
  const float* pts    = (const float*)d_in[0];
  const float* W1     = (const float*)d_in[1];
  const float* b1     = (const float*)d_in[2];
  const float* scale1 = (const float*)d_in[3];
  const float* bias1  = (const float*)d_in[4];
  const float* W2     = (const float*)d_in[5];
  const float* b2     = (const float*)d_in[6];
  const float* scale2 = (const float*)d_in[7];
  const float* bias2  = (const float*)d_in[8];
  const int*   seed   = (const int*)d_in[9];
  float* out = (float*)d_out;

  char* ws = (char*)d_ws;
  int*    sampled = (int*)(ws);
  int*    groups  = (int*)(ws + 8192);
  float4* xyzw    = (float4*)(ws + 532480);
  float*  stats   = (float*)(ws + 1581056);
  float* gsum1 = stats, *gss1 = stats + 512;
  float*  ac1     = (float*)(ws + 1589248);
  float*  ac2     = (float*)(ws + 1593344);
  float*  y2sel   = (float*)(ws + 1597440);          // 4 MB
  // slot aliases y2sel (disjoint lifetime): 65504 u64 = 524 KB < 4 MB region
  unsigned long long* slot = (unsigned long long*)(ws + 1597440);
  unsigned short* W2T = (unsigned short*)(ws + 5791744);   // 512 KB bf16
  float* st2      = (float*)(ws + 6316032);          // 32 x 1024 sliced bn2 stats

  k_init<<<256, 256, 0, stream>>>(pts, W2, seed, slot, stats, st2, W2T, xyzw, sampled);
  k_mega<<<MEGA_BLOCKS, 1024, MEGA_LDS, stream>>>(xyzw, pts, W1, b1, slot, sampled,
                                                  groups, gsum1, gss1);
  k_finalize<<<1, EMB, 0, stream>>>(gsum1, gss1, scale1, bias1, ac1);
  size_t mlp_lds = 3104 + (size_t)NGRP * H1B_S * sizeof(unsigned short);  // ~68 KB
  k_mlp<<<NSAMP, 512, mlp_lds, stream>>>(pts, sampled, groups, W1, b1, ac1,
                                         W2T, b2, scale2, st2, y2sel);
  k_finalize2<<<1, EMB, 0, stream>>>(st2, scale2, bias2, ac2);
  k_out<<<(out_size+255)/256, 256, 0, stream>>>(y2sel, ac2, out);
}

// Round 12
// 5157.449 us; speedup vs baseline: 1.0219x; 1.0219x over previous
//
#include <hip/hip_runtime.h>
#include <stdint.h>

#define N_PTS 65536
#define DIMS 6
#define NSAMP 2048
#define NGRP 64
#define EMB 512
#define ROWS (NSAMP*NGRP)
#define EPS_BN 1e-5f

#define FIRST_MODE 0

typedef __attribute__((ext_vector_type(8))) short short8;
typedef __attribute__((ext_vector_type(4))) float float4v;

__device__ __forceinline__ unsigned short f2bf(float f) {
  unsigned u = __float_as_uint(f);
  u += 0x7FFFu + ((u >> 16) & 1u);   // RNE
  return (unsigned short)(u >> 16);
}

// ---------------- Threefry-2x32, 20 rounds (JAX-compatible) ----------------
__device__ __forceinline__ void tf2x32(unsigned k0, unsigned k1, unsigned &x0, unsigned &x1) {
  unsigned ks[3] = {k0, k1, k0 ^ k1 ^ 0x1BD11BDAu};
  const unsigned R[8] = {13,15,26,6,17,29,16,24};
  x0 += ks[0]; x1 += ks[1];
#pragma unroll
  for (int g = 0; g < 5; ++g) {
#pragma unroll
    for (int j = 0; j < 4; ++j) {
      unsigned r = R[(g & 1) * 4 + j];
      x0 += x1;
      x1 = (x1 << r) | (x1 >> (32 - r));
      x1 ^= x0;
    }
    x0 += ks[(g + 1) % 3];
    x1 += ks[(g + 2) % 3] + (unsigned)(g + 1);
  }
}

__device__ __forceinline__ int compute_first(unsigned seed) {
  unsigned k0 = 0u, k1 = seed;
  unsigned s0, s1;
#if (FIRST_MODE == 0) || (FIRST_MODE == 1)
  { unsigned a0 = 0u, a1 = 1u; tf2x32(k0, k1, a0, a1); s0 = a0; s1 = a1; }
#else
  { unsigned p0 = 0u, p1 = 2u; tf2x32(k0, k1, p0, p1);
    unsigned q0 = 1u, q1 = 3u; tf2x32(k0, k1, q0, q1);
    s0 = p1; s1 = q1; }
#endif
  unsigned b0 = 0u, b1v = 0u; tf2x32(s0, s1, b0, b1v);
#if (FIRST_MODE == 0) || (FIRST_MODE == 3)
  unsigned bits = b0 ^ b1v;
#else
  unsigned bits = b0;
#endif
  return (int)(bits & 0xFFFFu);
}

// ---------------- geometry ---------------------------------------------------
#define FPSB 16                      // FPS blocks (16 slots = two 64B lines/iter)
#define MEGA_BLOCKS 256              // 16 FPS + 240 workers; 1 block/CU (LDS-forced)
#define FPS_PPT 4                    // 65536 / (16*1024)
#define GB_CAND 512
#define H1B_S 520                    // bf16 h1 LDS row stride (bank-benign)
#define MEGA_LDS 90112               // > 80 KB -> hardware cannot co-schedule 2 blocks/CU

// ---------------- init: xyzw, slots, stats, W2T(bf16), first idx ------------
__global__ __launch_bounds__(256) void k_init(const float* __restrict__ pts,
    const float* __restrict__ W2, const int* __restrict__ seed_arr,
    unsigned long long* __restrict__ slot, float* __restrict__ stats,
    float* __restrict__ st2, unsigned short* __restrict__ W2T,
    float4* __restrict__ xyzw, int* __restrict__ sampled) {
  int tid = blockIdx.x * 256 + threadIdx.x;        // 65536 threads
  if (tid < N_PTS) {
    float x = pts[tid*6], y = pts[tid*6+1], z = pts[tid*6+2];
    float p2 = __fadd_rn(__fadd_rn(__fmul_rn(x,x), __fmul_rn(y,y)), __fmul_rn(z,z));
    xyzw[tid] = make_float4(x, y, z, p2);
  }
#pragma unroll
  for (int i = 0; i < 4; ++i) {      // W2T[c][k] = bf16(W2[k][c]); writes coalesced
    int e = tid + i*65536;
    int c = e >> 9, k = e & 511;
    W2T[e] = f2bf(W2[k*EMB + c]);
  }
  if (tid < (NSAMP-1)*FPSB) slot[tid] = 0ull;
  if (tid < 4*EMB) stats[tid] = 0.f;
  if (tid < 32*1024) st2[tid] = 0.f;               // sliced bn2 stats
  if (tid >= 1 && tid < NSAMP) sampled[tid] = -1;  // sentinel for workers
  if (tid == 0) sampled[0] = compute_first((unsigned)seed_arr[0]);
}

// ---------------- mega: FPS blocks + group/stats worker blocks ---------------
// Measured-best protocol (R10): FPSB=16, relaxed agent atomics, leader-wave
// global poll, LDS-spin winner broadcast, 1 block/CU via 88 KB LDS.
// New: leader wave runs at s_setprio(3); follower waves drop to prio 0 during
// their LDS spin -- the leader's reduce->store->poll->broadcast chain is the
// serial critical path, so give it the CU's issue slots.
__global__ __launch_bounds__(1024) void k_mega(
    const float4* __restrict__ xyzw, const float* __restrict__ pts,
    const float* __restrict__ W1, const float* __restrict__ b1,
    unsigned long long* __restrict__ slot, int* __restrict__ sampled,
    int* __restrict__ groups, float* __restrict__ gsum, float* __restrict__ gss) {
  extern __shared__ __align__(16) char smraw[];
  const int t = threadIdx.x;
  if (blockIdx.x < FPSB) {
    // ------------------ FPS role ------------------
    unsigned long long* wred = (unsigned long long*)smraw;       // [2][16]
    volatile int* winLDS = (volatile int*)(smraw + 256);         // [2]
    const int b = blockIdx.x;
    const int T = b*1024 + t;                                    // 0..16383
    const int lane = t & 63, wid = t >> 6;
    float px[FPS_PPT], py[FPS_PPT], pz[FPS_PPT], pd[FPS_PPT];
    unsigned nidxu[FPS_PPT];
#pragma unroll
    for (int i = 0; i < FPS_PPT; ++i) {
      float4 p = xyzw[T + 16384*i];
      px[i] = p.x; py[i] = p.y; pz[i] = p.z; pd[i] = __builtin_inff();
      nidxu[i] = 0xFFFFFFFFu - (unsigned)(T + 16384*i);
    }
    if (t == 0) { winLDS[0] = -1; winLDS[1] = -1; }
    int last = sampled[0];
    if (wid == 0) __builtin_amdgcn_s_setprio(3);   // leader wave owns the chain
    __syncthreads();
    for (int it = 0; it < NSAMP-1; ++it) {
      const int p = it & 1;
      float4 cc = xyzw[last];
      unsigned long long best = 1ull;
#pragma unroll
      for (int i = 0; i < FPS_PPT; ++i) {
        float dx = __fsub_rn(px[i], cc.x);
        float dy = __fsub_rn(py[i], cc.y);
        float dz = __fsub_rn(pz[i], cc.z);
        float d = __fadd_rn(__fadd_rn(__fmul_rn(dx,dx), __fmul_rn(dy,dy)), __fmul_rn(dz,dz));
        pd[i] = fminf(pd[i], d);
        unsigned long long pk = ((unsigned long long)__float_as_uint(pd[i]) << 32)
                              | (unsigned long long)nidxu[i];
        best = best > pk ? best : pk;
      }
#pragma unroll
      for (int off = 32; off >= 1; off >>= 1) {
        unsigned long long o = __shfl_xor(best, off, 64);
        best = best > o ? best : o;
      }
      if (lane == 0) wred[p*16 + wid] = best;
      __syncthreads();
      if (wid == 0) {
        if (lane == 0) winLDS[1-p] = -1;   // safe: all waves past prev spin
        unsigned long long m = wred[p*16 + (lane & 15)];
#pragma unroll
        for (int off = 8; off >= 1; off >>= 1) {
          unsigned long long o = __shfl_xor(m, off, 64);
          m = m > o ? m : o;
        }
        if (lane == 0)
          __hip_atomic_store(&slot[it*FPSB + b], m,
                             __ATOMIC_RELAXED, __HIP_MEMORY_SCOPE_AGENT);
        unsigned long long v = 0ull;
        if (lane < FPSB) {
          const unsigned long long* sp = &slot[it*FPSB + lane];
          v = __hip_atomic_load(sp, __ATOMIC_RELAXED, __HIP_MEMORY_SCOPE_AGENT);
          while (v == 0ull)
            v = __hip_atomic_load(sp, __ATOMIC_RELAXED, __HIP_MEMORY_SCOPE_AGENT);
        }
#pragma unroll
        for (int off = 8; off >= 1; off >>= 1) {
          unsigned long long o = __shfl_xor(v, off, 64);
          v = v > o ? v : o;
        }
        v = __shfl(v, 0, 64);
        int win = (int)(0xFFFFFFFFu - (unsigned)(v & 0xFFFFFFFFull));
        if (lane == 0) {
          if (b == 0)
            __hip_atomic_store((unsigned*)&sampled[it+1], (unsigned)win,
                               __ATOMIC_RELAXED, __HIP_MEMORY_SCOPE_AGENT);
          winLDS[p] = win;
        }
        last = win;
      } else {
        __builtin_amdgcn_s_setprio(0);
        int w = winLDS[p];
        while (w == -1) { __builtin_amdgcn_s_sleep(1); w = winLDS[p]; }
        __builtin_amdgcn_s_setprio(1);
        last = w;
      }
    }
  } else {
    // ------------------ worker role: group + bn1 stats ------------------
    unsigned* hist  = (unsigned*)smraw;              // 8192
    unsigned* scan  = (unsigned*)(smraw + 32768);    // 1024
    unsigned* candK = (unsigned*)(smraw + 36864);    // 512
    int*      candI = (int*)(smraw + 38912);         // 512
    float*    feat  = (float*)(smraw + 40960);       // 768
    float*    cf    = (float*)(smraw + 44032);       // 8
    unsigned* ctl   = (unsigned*)(smraw + 44064);    // outcnt, candcnt
    volatile int* binfo = (volatile int*)(smraw + 44080); // B, bef, sid
    const int wkr = blockIdx.x - FPSB;               // 0..239
    for (int s = wkr; s < NSAMP; s += MEGA_BLOCKS - FPSB) {
      if (t == 0) {
        unsigned v = __hip_atomic_load((const unsigned*)&sampled[s],
                        __ATOMIC_RELAXED, __HIP_MEMORY_SCOPE_AGENT);
        while (v == 0xFFFFFFFFu) {
          __builtin_amdgcn_s_sleep(64);
          v = __hip_atomic_load((const unsigned*)&sampled[s],
                  __ATOMIC_RELAXED, __HIP_MEMORY_SCOPE_AGENT);
        }
        binfo[2] = (int)v;
        ctl[0] = 0u; ctl[1] = 0u;
      }
      for (int k = t; k < 8192; k += 1024) hist[k] = 0u;
      __syncthreads();
      const int sid = binfo[2];
      float4 c4 = xyzw[sid];
      const float cx=c4.x, cy=c4.y, cz=c4.z, c2=c4.w;
      for (int i = 0; i < N_PTS/1024; ++i) {
        int j = i*1024 + t;
        float4 p = xyzw[j];
        float dot = __fadd_rn(__fadd_rn(__fmul_rn(cx,p.x),__fmul_rn(cy,p.y)),__fmul_rn(cz,p.z));
        float d = __fsub_rn(__fadd_rn(c2, p.w), __fmul_rn(2.0f, dot));
        unsigned kb = __float_as_uint(d);
        kb ^= ((unsigned)((int)kb >> 31)) | 0x80000000u;
        atomicAdd(&hist[kb >> 19], 1u);
      }
      __syncthreads();
      unsigned ch = 0u;
      for (int k = 0; k < 8; ++k) ch += hist[t*8 + k];
      scan[t] = ch;
      __syncthreads();
      for (int off = 1; off < 1024; off <<= 1) {
        unsigned vv = (t >= off) ? scan[t - off] : 0u;
        __syncthreads();
        scan[t] += vv;
        __syncthreads();
      }
      unsigned inc = scan[t], before = inc - ch;
      if (before < NGRP && inc >= NGRP) {
        unsigned c = before;
        for (int k = 0; k < 8; ++k) {
          unsigned nb = hist[t*8 + k];
          if (c + nb >= NGRP) { binfo[0] = t*8 + k; binfo[1] = (int)c; break; }
          c += nb;
        }
      }
      __syncthreads();
      const unsigned B = (unsigned)binfo[0];
      const int bef = binfo[1];
      for (int i = 0; i < N_PTS/1024; ++i) {
        int j = i*1024 + t;
        float4 p = xyzw[j];
        float dot = __fadd_rn(__fadd_rn(__fmul_rn(cx,p.x),__fmul_rn(cy,p.y)),__fmul_rn(cz,p.z));
        float d = __fsub_rn(__fadd_rn(c2, p.w), __fmul_rn(2.0f, dot));
        unsigned kb = __float_as_uint(d);
        kb ^= ((unsigned)((int)kb >> 31)) | 0x80000000u;
        unsigned bin = kb >> 19;
        if (bin < B) {
          unsigned pos = atomicAdd(&ctl[0], 1u);
          groups[s*NGRP + pos] = j;
        } else if (bin == B) {
          unsigned ci = atomicAdd(&ctl[1], 1u);
          if (ci < GB_CAND) { candK[ci] = kb; candI[ci] = j; }
        }
      }
      __syncthreads();
      int M = ctl[1] < GB_CAND ? (int)ctl[1] : GB_CAND;
      int need = NGRP - bef;
      for (int c = t; c < M; c += 1024) {
        unsigned mk = candK[c]; int mi = candI[c];
        int rank = 0;
        for (int q = 0; q < M; ++q) {
          unsigned qk = candK[q];
          rank += (qk < mk || (qk == mk && candI[q] < mi)) ? 1 : 0;
        }
        if (rank < need) {
          unsigned pos = atomicAdd(&ctl[0], 1u);
          groups[s*NGRP + pos] = candI[c];
        }
      }
      __syncthreads();
      if (t == 0) {
        while (ctl[0] < NGRP) { groups[s*NGRP + ctl[0]] = 0; ctl[0]++; }
      }
      __syncthreads();
      if (t < DIMS) cf[t] = pts[sid*6 + t];
      __syncthreads();
      if (t < NGRP) {
        int g = groups[s*NGRP + t];
#pragma unroll
        for (int k = 0; k < DIMS; ++k) {
          float v = pts[g*6 + k];
          feat[t*12 + k] = v - cf[k];
          feat[t*12 + 6 + k] = v;
        }
      }
      __syncthreads();
      if (t < EMB) {
        float w[12];
#pragma unroll
        for (int k = 0; k < 12; ++k) w[k] = W1[k*EMB + t];
        float b = b1[t];
        float sum = 0.f, ss = 0.f;
        for (int r = 0; r < NGRP; ++r) {
          float y = b;
#pragma unroll
          for (int k = 0; k < 12; ++k) y += feat[r*12+k] * w[k];
          sum += y; ss += y*y;
        }
        atomicAdd(&gsum[t], sum);
        atomicAdd(&gss[t], ss);
      }
      __syncthreads();   // smraw reused next s
    }
  }
}

// ---------------- bn1 finalize ----------------------------------------------
__global__ __launch_bounds__(EMB) void k_finalize(const float* __restrict__ gsum,
    const float* __restrict__ gss, const float* __restrict__ scale,
    const float* __restrict__ bias, float* __restrict__ ac) {
  int c = threadIdx.x;
  float inv = 1.f / (float)ROWS;
  float mean = gsum[c] * inv;
  float var = gss[c] * inv - mean*mean;
  var = var < 0.f ? 0.f : var;
  float a = scale[c] * rsqrtf(var + EPS_BN);
  ac[c] = a; ac[EMB + c] = bias[c] - mean * a;
}

// ---------------- bn2 finalize from 32-sliced stats -------------------------
__global__ __launch_bounds__(EMB) void k_finalize2(const float* __restrict__ st2,
    const float* __restrict__ scale, const float* __restrict__ bias,
    float* __restrict__ ac) {
  int c = threadIdx.x;
  float sum = 0.f, ss = 0.f;
  for (int i = 0; i < 32; ++i) {
    sum += st2[i*1024 + c];
    ss  += st2[i*1024 + 512 + c];
  }
  float inv = 1.f / (float)ROWS;
  float mean = sum * inv;
  float var = ss * inv - mean*mean;
  var = var < 0.f ? 0.f : var;
  float a = scale[c] * rsqrtf(var + EPS_BN);
  ac[c] = a; ac[EMB + c] = bias[c] - mean * a;
}

// ---------------- fused MLP: fp32 GEMM1 -> bf16 MFMA GEMM2 ------------------
__global__ __launch_bounds__(512, 4) void k_mlp(const float* __restrict__ pts,
    const int* __restrict__ sampled, const int* __restrict__ groups,
    const float* __restrict__ W1, const float* __restrict__ b1,
    const float* __restrict__ ac1, const unsigned short* __restrict__ W2T,
    const float* __restrict__ b2, const float* __restrict__ scale2,
    float* __restrict__ st2, float* __restrict__ y2sel) {
  const int s = blockIdx.x, t = threadIdx.x;
  extern __shared__ __align__(16) char smc[];
  float* feat = (float*)smc;                       // 768 f
  float* cf   = (float*)(smc + 3072);              // 8 f
  unsigned short* h1b = (unsigned short*)(smc + 3104);  // 64 x 520 bf16
  if (t < DIMS) cf[t] = pts[sampled[s]*6 + t];
  __syncthreads();
  if (t < NGRP) {
    int g = groups[s*NGRP + t];
#pragma unroll
    for (int k = 0; k < DIMS; ++k) {
      float v = pts[g*6 + k];
      feat[t*12+k]   = v - cf[k];
      feat[t*12+6+k] = v;
    }
  }
  __syncthreads();
  {
    float w[12];
#pragma unroll
    for (int k = 0; k < 12; ++k) w[k] = W1[k*EMB + t];
    float b = b1[t], a1 = ac1[t], c1 = ac1[EMB + t];
    for (int r = 0; r < NGRP; ++r) {
      float y = b;
#pragma unroll
      for (int k = 0; k < 12; ++k) y += feat[r*12+k] * w[k];
      float hv = a1*y + c1;
      h1b[r*H1B_S + t] = f2bf(hv > 0.f ? hv : 0.f);
    }
  }
  __syncthreads();
  const int lane = t & 63, w = t >> 6;
  const int quad = lane >> 4, l16 = lane & 15;
  float4v acc[4][4];
#pragma unroll
  for (int nt = 0; nt < 4; ++nt) {
    float bv = b2[(w*4+nt)*16 + l16];
#pragma unroll
    for (int mt = 0; mt < 4; ++mt)
      acc[nt][mt] = (float4v){bv, bv, bv, bv};
  }
  for (int kc = 0; kc < 16; ++kc) {
    const int kb = kc*32 + quad*8;
    short8 af[4];
#pragma unroll
    for (int mt = 0; mt < 4; ++mt)
      af[mt] = *(const short8*)&h1b[(mt*16 + l16)*H1B_S + kb];
#pragma unroll
    for (int nt = 0; nt < 4; ++nt) {
      const int c = (w*4+nt)*16 + l16;
      short8 bf = *(const short8*)&W2T[c*EMB + kb];
#pragma unroll
      for (int mt = 0; mt < 4; ++mt)
        acc[nt][mt] = __builtin_amdgcn_mfma_f32_16x16x32_bf16(af[mt], bf, acc[nt][mt], 0, 0, 0);
    }
  }
#pragma unroll
  for (int nt = 0; nt < 4; ++nt) {
    float sm_ = 0.f, ss_ = 0.f, mx = -__builtin_inff(), mn = __builtin_inff();
#pragma unroll
    for (int mt = 0; mt < 4; ++mt)
#pragma unroll
      for (int i = 0; i < 4; ++i) {
        float v = acc[nt][mt][i];
        sm_ += v; ss_ += v*v;
        mx = fmaxf(mx, v); mn = fminf(mn, v);
      }
#pragma unroll
    for (int off = 16; off <= 32; off <<= 1) {
      sm_ += __shfl_xor(sm_, off, 64);
      ss_ += __shfl_xor(ss_, off, 64);
      mx = fmaxf(mx, __shfl_xor(mx, off, 64));
      mn = fminf(mn, __shfl_xor(mn, off, 64));
    }
    if (quad == 0) {
      int c = (w*4+nt)*16 + l16;
      atomicAdd(&st2[(s & 31)*1024 + c], sm_);
      atomicAdd(&st2[(s & 31)*1024 + 512 + c], ss_);
      y2sel[s*EMB + c] = (scale2[c] >= 0.f) ? mx : mn;
    }
  }
}

// ---------------- epilogue: bn2+relu on pooled extremum ---------------------
__global__ __launch_bounds__(256) void k_out(const float* __restrict__ y2sel,
    const float* __restrict__ ac2, float* __restrict__ out) {
  int i = blockIdx.x*256 + threadIdx.x;
  int c = i & (EMB-1);
  float a = ac2[c], cc = ac2[EMB + c];
  float v = a*y2sel[i] + cc;
  out[i] = v > 0.f ? v : 0.f;
}

extern "C" void kernel_launch(void* const* d_in, const int* in_sizes, int n_in,
                              void* d_out, int out_size, void* d_ws, size_t ws_size,
                              hipStream_t stream) {
  const float* pts    = (const float*)d_in[0];
  const float* W1     = (const float*)d_in[1];
  const float* b1     = (const float*)d_in[2];
  const float* scale1 = (const float*)d_in[3];
  const float* bias1  = (const float*)d_in[4];
  const float* W2     = (const float*)d_in[5];
  const float* b2     = (const float*)d_in[6];
  const float* scale2 = (const float*)d_in[7];
  const float* bias2  = (const float*)d_in[8];
  const int*   seed   = (const int*)d_in[9];
  float* out = (float*)d_out;

  char* ws = (char*)d_ws;
  int*    sampled = (int*)(ws);
  int*    groups  = (int*)(ws + 8192);
  float4* xyzw    = (float4*)(ws + 532480);
  float*  stats   = (float*)(ws + 1581056);
  float* gsum1 = stats, *gss1 = stats + 512;
  float*  ac1     = (float*)(ws + 1589248);
  float*  ac2     = (float*)(ws + 1593344);
  float*  y2sel   = (float*)(ws + 1597440);          // 4 MB
  // slot aliases y2sel (disjoint lifetime): 2047*16 u64 = 262KB < 4MB region
  unsigned long long* slot = (unsigned long long*)(ws + 1597440);
  unsigned short* W2T = (unsigned short*)(ws + 5791744);   // 512 KB bf16
  float* st2      = (float*)(ws + 6316032);          // 32 x 1024 sliced bn2 stats

  k_init<<<256, 256, 0, stream>>>(pts, W2, seed, slot, stats, st2, W2T, xyzw, sampled);
  k_mega<<<MEGA_BLOCKS, 1024, MEGA_LDS, stream>>>(xyzw, pts, W1, b1, slot, sampled,
                                                  groups, gsum1, gss1);
  k_finalize<<<1, EMB, 0, stream>>>(gsum1, gss1, scale1, bias1, ac1);
  size_t mlp_lds = 3104 + (size_t)NGRP * H1B_S * sizeof(unsigned short);  // ~68 KB
  k_mlp<<<NSAMP, 512, mlp_lds, stream>>>(pts, sampled, groups, W1, b1, ac1,
                                         W2T, b2, scale2, st2, y2sel);
  k_finalize2<<<1, EMB, 0, stream>>>(st2, scale2, bias2, ac2);
  k_out<<<(out_size+255)/256, 256, 0, stream>>>(y2sel, ac2, out);
}